// Round 7
// baseline (382.594 us; speedup 1.0000x reference)
//
#include <hip/hip_runtime.h>
#include <hip/hip_bf16.h>

typedef unsigned short u16;
typedef __attribute__((ext_vector_type(8))) __bf16 bf16x8;
typedef __attribute__((ext_vector_type(4))) float f32x4;

// Problem dims
#define BB 32
#define LL 512
#define CC 512
#define HH 8
#define DH 64
#define MROWS (BB * LL)        // 16384
#define NQKV  (3 * CC)         // 1536

// workspace layout (bytes)
#define XB_BYTES ((size_t)MROWS * CC * 2)        // x bf16 (reused as vT)
#define WC_BYTES ((size_t)NQKV * CC * 2)         // wq|wk|wv bf16
#define QKV_OFF  (XB_BYTES + WC_BYTES)           // qkv bf16: MROWS x 1536

// softmax scale (512^-0.5) * log2(e), folded into wq at cvt: QK^T MFMA output
// is already exp2-domain. No max-subtract (scores' std ~0.07; validated R4/R5).
#define SCALE2 (0.044194173824159216f * 1.4426950408889634f)

__device__ inline u16 f2b(float f) {
  union { float f; unsigned u; } a; a.f = f;
  unsigned u = a.u;
  return (u16)((u + 0x7FFFu + ((u >> 16) & 1u)) >> 16);
}

__device__ inline unsigned pack2(float a, float b) {  // v_cvt_pk_bf16_f32
  float2 f; f.x = a; f.y = b;
  union { __hip_bfloat162 h; unsigned u; } c;
  c.h = __float22bfloat162_rn(f);
  return c.u;
}

// ---------------- conversion kernels ----------------
__global__ __launch_bounds__(256) void cvt_x(const float* __restrict__ x, u16* __restrict__ xb) {
  int i = blockIdx.x * 256 + threadIdx.x;
  float4 v = ((const float4*)x)[i];
  uint2 o; o.x = pack2(v.x, v.y); o.y = pack2(v.z, v.w);
  ((uint2*)xb)[i] = o;
}

__global__ __launch_bounds__(256) void cvt_w(const float* __restrict__ wq, const float* __restrict__ wk,
                                             const float* __restrict__ wv, u16* __restrict__ wcat) {
  int i = blockIdx.x * 256 + threadIdx.x;
  int e = i * 4;
  int n = e >> 9;
  int k = e & 511;
  const float* src = (n < 512) ? (wq + (size_t)n * 512)
                   : (n < 1024) ? (wk + (size_t)(n - 512) * 512)
                                : (wv + (size_t)(n - 1024) * 512);
  const float sc = (n < 512) ? SCALE2 : 1.0f;
  float4 v = *(const float4*)(src + k);
  uint2 o; o.x = pack2(v.x * sc, v.y * sc); o.y = pack2(v.z * sc, v.w * sc);
  *(uint2*)(wcat + (size_t)n * 512 + k) = o;
}

// ---------------- async global->LDS ----------------
typedef __attribute__((address_space(1))) void* as1_void_p;
typedef __attribute__((address_space(3))) void* as3_void_p;

__device__ inline void async16(const u16* g, u16* l) {
#if __has_builtin(__builtin_amdgcn_global_load_lds)
  __builtin_amdgcn_global_load_lds((as1_void_p)g, (as3_void_p)l, 16, 0, 0);
#else
  *(uint4*)l = *(const uint4*)g;
#endif
}

// ---------------- QKV projection GEMM (m97-style, unchanged) ----------------
__global__ __launch_bounds__(256) void gemm_qkv(const u16* __restrict__ A, const u16* __restrict__ Bw,
                                                u16* __restrict__ Cm) {
  __shared__ u16 a_lds[128 * 32];
  __shared__ u16 b_lds[128 * 32];
  const int n0 = blockIdx.x * 128, m0 = blockIdx.y * 128;
  const int t = threadIdx.x, l = t & 63;
  const int wrow = ((t >> 7) & 1) * 64, wcol = ((t >> 6) & 1) * 64;
  const int lr = l & 15, lq = l >> 4;

  f32x4 acc[4][4] = {};

  for (int k0 = 0; k0 < 512; k0 += 32) {
    {
      int c0 = t, c1 = t + 256;
      async16(A  + (size_t)(m0 + (c0 >> 2)) * 512 + k0 + (c0 & 3) * 8, &a_lds[c0 * 8]);
      async16(A  + (size_t)(m0 + (c1 >> 2)) * 512 + k0 + (c1 & 3) * 8, &a_lds[c1 * 8]);
      async16(Bw + (size_t)(n0 + (c0 >> 2)) * 512 + k0 + (c0 & 3) * 8, &b_lds[c0 * 8]);
      async16(Bw + (size_t)(n0 + (c1 >> 2)) * 512 + k0 + (c1 & 3) * 8, &b_lds[c1 * 8]);
    }
    __syncthreads();
    bf16x8 af[4], bfr[4];
#pragma unroll
    for (int r = 0; r < 4; ++r) af[r]  = *(const bf16x8*)&a_lds[(wrow + r * 16 + lr) * 32 + lq * 8];
#pragma unroll
    for (int c = 0; c < 4; ++c) bfr[c] = *(const bf16x8*)&b_lds[(wcol + c * 16 + lr) * 32 + lq * 8];
#pragma unroll
    for (int r = 0; r < 4; ++r)
#pragma unroll
      for (int c = 0; c < 4; ++c)
        acc[r][c] = __builtin_amdgcn_mfma_f32_16x16x32_bf16(af[r], bfr[c], acc[r][c], 0, 0, 0);
    __syncthreads();
  }
#pragma unroll
  for (int r = 0; r < 4; ++r) {
#pragma unroll
    for (int i = 0; i < 4; ++i) {
      int m = m0 + wrow + r * 16 + lq * 4 + i;
      u16* crow = Cm + (size_t)m * NQKV + n0 + wcol;
#pragma unroll
      for (int c = 0; c < 4; ++c)
        crow[c * 16 + lr] = f2b(acc[r][c][i]);
    }
  }
}

// ---------------- V transpose: qkv V-part (b,l,h,d) -> vT[(b*8+h)*64+d][l] ----------------
__global__ __launch_bounds__(256) void transpose_v(const u16* __restrict__ qkv, u16* __restrict__ vT) {
  const int bh = blockIdx.x;
  const int b = bh >> 3, h = bh & 7;
  const int lc0 = blockIdx.y * 128;
  __shared__ u16 tile[32 * 72];
  const int t = threadIdx.x;
  for (int lc = lc0; lc < lc0 + 128; lc += 32) {
    int lrow = t >> 3, dcol = (t & 7) * 8;
    const u16* src = qkv + (size_t)(b * 512 + lc + lrow) * NQKV + 1024 + h * 64 + dcol;
    *(uint4*)&tile[lrow * 72 + dcol] = *(const uint4*)src;
    __syncthreads();
    int d = t >> 2, lp = (t & 3) * 8;
    union { ushort4 v4[2]; u16 s[8]; } tmp;
#pragma unroll
    for (int j = 0; j < 8; ++j) tmp.s[j] = tile[(lp + j) * 72 + d];
    *(uint4*)&vT[(size_t)(bh * 64 + d) * 512 + lc + lp] = *(uint4*)&tmp;
    __syncthreads();
  }
}

// ---------------- wave-autonomous chunked attention, ZERO barriers ----------------
// Block = 4 independent waves. Wave w: (b, h, 16 queries q0 = (qg*4+w)*16),
// streams keys in 32-chunks: S^T = K Q^T (exp2-domain) -> exp2 -> pack bf16
// -> per-wave LDS slice (16 rows x stride 40: b128 reads hit all 8 bank-groups
// per phase; same-wave DS ops are in-order, no barrier) -> PV MFMA on
// UNNORMALIZED P; rinv applied at the end. Bias enters as its own MFMA B-frag
// (truncated-bf16 reads of the table's fp32 high halves, imm-offset loads):
// out = accP*rinv + accB.
// Grid flat = h | (qg<<3) | (b<<6): XCD (flat%8) = h -> K/V L2 locality (R5-validated).
__global__ __launch_bounds__(256) void attn_kernel(const u16* __restrict__ qkv, const u16* __restrict__ vT,
                                                   const float* __restrict__ bias_table,
                                                   float* __restrict__ out) {
  __shared__ u16 p_lds[4][16 * 40];          // 5 KB total, per-wave slices
  const int flat = blockIdx.x;
  const int h = flat & 7, qg = (flat >> 3) & 7, b = flat >> 6;
  const int t = threadIdx.x, w = t >> 6, l = t & 63;
  const int lr = l & 15, lq = l >> 4;
  const int q0 = (qg * 4 + w) * 16;

  // Q B-frag (pre-scaled by SCALE2 via cvt_w)
  const u16* qrow = qkv + (size_t)(b * 512 + q0 + lr) * NQKV + h * 64;
  bf16x8 bq0 = *(const bf16x8*)(qrow + lq * 8);
  bf16x8 bq1 = *(const bf16x8*)(qrow + 32 + lq * 8);

  u16* ps = p_lds[w];
  // bias base: rel = key - (q0+lr) + 511 >= 0; table row = 8 floats = 16 u16
  const u16* tb = (const u16*)bias_table + (size_t)(511 - q0 - lr) * 16 + h * 2 + 1;
  const u16* kbase = qkv + (size_t)(b * 512) * NQKV + 512 + h * 64;
  const u16* vbase = vT + (size_t)((b * 8 + h) * 64) * 512;

  f32x4 accP[4] = {}, accB[4] = {};
  float ssum = 0.f;

#pragma unroll 2
  for (int kb = 0; kb < 16; ++kb) {
    // --- S^T chunk: keys [kb*32, +32) ---
    const u16* k0 = kbase + (size_t)(kb * 32 + lr) * NQKV;
    const u16* k1 = k0 + (size_t)16 * NQKV;
    bf16x8 a00 = *(const bf16x8*)(k0 + lq * 8);
    bf16x8 a01 = *(const bf16x8*)(k0 + 32 + lq * 8);
    bf16x8 a10 = *(const bf16x8*)(k1 + lq * 8);
    bf16x8 a11 = *(const bf16x8*)(k1 + 32 + lq * 8);
    f32x4 s0 = {0.f, 0.f, 0.f, 0.f}, s1 = {0.f, 0.f, 0.f, 0.f};
    s0 = __builtin_amdgcn_mfma_f32_16x16x32_bf16(a00, bq0, s0, 0, 0, 0);
    s0 = __builtin_amdgcn_mfma_f32_16x16x32_bf16(a01, bq1, s0, 0, 0, 0);
    s1 = __builtin_amdgcn_mfma_f32_16x16x32_bf16(a10, bq0, s1, 0, 0, 0);
    s1 = __builtin_amdgcn_mfma_f32_16x16x32_bf16(a11, bq1, s1, 0, 0, 0);

    // --- exp2 (already exp2-domain), accumulate denominator ---
    float e0[4], e1[4];
#pragma unroll
    for (int i = 0; i < 4; ++i) { e0[i] = exp2f(s0[i]); e1[i] = exp2f(s1[i]); }
#pragma unroll
    for (int i = 0; i < 4; ++i) ssum += e0[i] + e1[i];

    // --- pack -> per-wave LDS slice (row q=lr, stride 40; chunk-local keys) ---
    uint2 pk0, pk1;
    pk0.x = pack2(e0[0], e0[1]); pk0.y = pack2(e0[2], e0[3]);
    pk1.x = pack2(e1[0], e1[1]); pk1.y = pack2(e1[2], e1[3]);
    *(uint2*)&ps[lr * 40 + lq * 4] = pk0;        // keys lq*4+i
    *(uint2*)&ps[lr * 40 + 16 + lq * 4] = pk1;   // keys 16+lq*4+i
    // --- read back as B-frag (same wave: DS in-order, no barrier) ---
    bf16x8 bp = *(const bf16x8*)&ps[lr * 40 + lq * 8];

    // --- bias B-frag: truncated bf16 of table[rel], imm-offset u16 loads ---
    union { bf16x8 v; u16 s[8]; } bfr;
    const u16* tkb = tb + (size_t)(kb * 32 + lq * 8) * 16;
#pragma unroll
    for (int j = 0; j < 8; ++j) bfr.s[j] = tkb[j * 16];

    // --- PV + biasV accumulate over d-tiles ---
#pragma unroll
    for (int dt = 0; dt < 4; ++dt) {
      bf16x8 av = *(const bf16x8*)(vbase + (size_t)(dt * 16 + lr) * 512 + kb * 32 + lq * 8);
      accP[dt] = __builtin_amdgcn_mfma_f32_16x16x32_bf16(av, bp, accP[dt], 0, 0, 0);
      accB[dt] = __builtin_amdgcn_mfma_f32_16x16x32_bf16(av, bfr.v, accB[dt], 0, 0, 0);
    }
  }

  // denominator: sum across lq groups (keys split over lq only)
  ssum += __shfl_xor(ssum, 16, 64);
  ssum += __shfl_xor(ssum, 32, 64);
  const float rinv = 1.0f / ssum;

  // epilogue: C layout lane (q=lr, d = dt*16 + lq*4 + i) -> coalesced f32x4
  float* orow = out + (size_t)(b * 512 + q0 + lr) * 512 + h * 64;
#pragma unroll
  for (int dt = 0; dt < 4; ++dt) {
    f32x4 o;
#pragma unroll
    for (int i = 0; i < 4; ++i) o[i] = accP[dt][i] * rinv + accB[dt][i];
    *(f32x4*)(orow + dt * 16 + lq * 4) = o;
  }
}

// ---------------- LayerNorm: 2 rows/block, float4 ----------------
__global__ __launch_bounds__(256) void ln_kernel(float* __restrict__ out,
                                                 const float* __restrict__ gamma,
                                                 const float* __restrict__ beta) {
  const int t = threadIdx.x;
  const int r2 = t >> 7;
  const int row = blockIdx.x * 2 + r2;
  const int c = (t & 127) * 4;
  float* p = out + (size_t)row * 512;
  float4 v = *(float4*)(p + c);
  float s = v.x + v.y + v.z + v.w;
  float s2 = v.x * v.x + v.y * v.y + v.z * v.z + v.w * v.w;
#pragma unroll
  for (int d = 1; d < 64; d <<= 1) { s += __shfl_xor(s, d, 64); s2 += __shfl_xor(s2, d, 64); }
  __shared__ float ps[4], ps2[4];
  const int wv = t >> 6;
  if ((t & 63) == 0) { ps[wv] = s; ps2[wv] = s2; }
  __syncthreads();
  s  = ps[r2 * 2]  + ps[r2 * 2 + 1];
  s2 = ps2[r2 * 2] + ps2[r2 * 2 + 1];
  float mu = s * (1.0f / 512.0f);
  float var = s2 * (1.0f / 512.0f) - mu * mu;
  float rs = rsqrtf(var + 1e-5f);
  float4 g = *(const float4*)(gamma + c);
  float4 bb = *(const float4*)(beta + c);
  v.x = g.x * (v.x - mu) * rs + bb.x;
  v.y = g.y * (v.y - mu) * rs + bb.y;
  v.z = g.z * (v.z - mu) * rs + bb.z;
  v.w = g.w * (v.w - mu) * rs + bb.w;
  *(float4*)(p + c) = v;
}

extern "C" void kernel_launch(void* const* d_in, const int* in_sizes, int n_in,
                              void* d_out, int out_size, void* d_ws, size_t ws_size,
                              hipStream_t stream) {
  const float* x    = (const float*)d_in[0];
  const float* wq   = (const float*)d_in[1];
  const float* wk   = (const float*)d_in[2];
  const float* wv   = (const float*)d_in[3];
  const float* bias = (const float*)d_in[4];
  const float* gamma = (const float*)d_in[5];
  const float* beta  = (const float*)d_in[6];
  float* out = (float*)d_out;

  char* ws = (char*)d_ws;
  u16* xb   = (u16*)ws;                       // x bf16 (reused as vT afterwards)
  u16* wcat = (u16*)(ws + XB_BYTES);          // concat weights bf16 (wq pre-scaled)
  u16* qkv  = (u16*)(ws + QKV_OFF);           // MROWS x 1536 bf16
  u16* vT   = xb;

  cvt_x<<<dim3((MROWS * CC) / 4 / 256), 256, 0, stream>>>(x, xb);
  cvt_w<<<dim3((NQKV * CC) / 4 / 256), 256, 0, stream>>>(wq, wk, wv, wcat);
  gemm_qkv<<<dim3(NQKV / 128, MROWS / 128), 256, 0, stream>>>(xb, wcat, qkv);
  transpose_v<<<dim3(256, 4), 256, 0, stream>>>(qkv, vT);
  attn_kernel<<<dim3(BB * 64), 256, 0, stream>>>(qkv, vT, bias, out);
  ln_kernel<<<dim3(MROWS / 2), 256, 0, stream>>>(out, gamma, beta);
}